// Round 1
// baseline (634.396 us; speedup 1.0000x reference)
//
#include <hip/hip_runtime.h>

#define N_NODES 100000
#define F_IN 128
#define HDIM 16

// ---------------- degree / norm ----------------

__global__ void k_fill1(float* __restrict__ deg, int n) {
    int i = blockIdx.x * blockDim.x + threadIdx.x;
    if (i < n) deg[i] = 1.0f;  // self-loop
}

__global__ void k_count(const int* __restrict__ dst, float* __restrict__ deg, int E) {
    int e = blockIdx.x * blockDim.x + threadIdx.x;
    if (e < E) atomicAdd(&deg[dst[e]], 1.0f);
}

__global__ void k_rsqrt(float* __restrict__ deg, int n) {
    int i = blockIdx.x * blockDim.x + threadIdx.x;
    if (i < n) deg[i] = rsqrtf(deg[i]);  // deg >= 1 always (self-loop)
}

// ---------------- layer 1 dense: h1 = x @ W1 ; out1 = h1*dinv^2 + b1 ----------------
// block = 256 threads, 16 nodes per block. W1 (128x16) and x-tile (16x128) staged in LDS.

__global__ __launch_bounds__(256) void k_h1(
        const float* __restrict__ x, const float* __restrict__ W1,
        const float* __restrict__ b1, const float* __restrict__ dinv,
        float* __restrict__ h1, float* __restrict__ out1) {
    __shared__ float ws[F_IN * HDIM];      // [k][col] row-major, 8 KB
    __shared__ float xs[16][F_IN + 1];     // +1 pad: kill 4-way bank conflict on column reads
    const int t = threadIdx.x;
    const int node0 = blockIdx.x * 16;

    for (int i = t; i < F_IN * HDIM; i += 256) ws[i] = W1[i];
    for (int i = t; i < 16 * F_IN; i += 256) {
        int r = i >> 7, c = i & 127;
        int n = node0 + r;
        xs[r][c] = (n < N_NODES) ? x[n * F_IN + c] : 0.0f;
    }
    __syncthreads();

    const int row = t >> 4, col = t & 15;
    const int node = node0 + row;
    float acc = 0.0f;
#pragma unroll 8
    for (int k = 0; k < F_IN; ++k)
        acc += xs[row][k] * ws[k * HDIM + col];

    if (node < N_NODES) {
        h1[node * HDIM + col] = acc;
        float di = dinv[node];
        // self-loop term + bias also zero-initializes the accumulation buffer
        out1[node * HDIM + col] = acc * di * di + b1[col];
    }
}

// ---------------- edge scatter: out[dst] += dinv[src]*dinv[dst] * h[src] ----------------
// 16 threads per edge (one per feature): coalesced 64B gather of h[src], 64B atomic scatter.

__global__ __launch_bounds__(256) void k_edge(
        const int* __restrict__ src, const int* __restrict__ dst,
        const float* __restrict__ dinv, const float* __restrict__ h,
        float* __restrict__ out, int E) {
    long long tid = (long long)blockIdx.x * blockDim.x + threadIdx.x;
    int e = (int)(tid >> 4);
    int c = (int)(tid & 15);
    if (e >= E) return;
    int s = src[e], d = dst[e];
    float norm = dinv[s] * dinv[d];
    atomicAdd(&out[d * HDIM + c], norm * h[s * HDIM + c]);
}

// ---------------- layer 2 dense: h2 = relu(out1) @ W2 ; out = h2*dinv^2 + b2 ----------------

__global__ __launch_bounds__(256) void k_h2(
        const float* __restrict__ out1, const float* __restrict__ W2,
        const float* __restrict__ b2, const float* __restrict__ dinv,
        float* __restrict__ h2, float* __restrict__ out) {
    __shared__ float ws[HDIM * HDIM];
    __shared__ float as[16][HDIM + 1];
    const int t = threadIdx.x;
    const int node0 = blockIdx.x * 16;

    if (t < HDIM * HDIM) ws[t] = W2[t];
    {   // 16 nodes x 16 feats = 256 contiguous floats, one per thread; apply relu on load
        int n = node0 + (t >> 4);
        float v = (n < N_NODES) ? out1[node0 * HDIM + t] : 0.0f;
        as[t >> 4][t & 15] = fmaxf(v, 0.0f);
    }
    __syncthreads();

    const int row = t >> 4, col = t & 15;
    const int node = node0 + row;
    float acc = 0.0f;
#pragma unroll
    for (int k = 0; k < HDIM; ++k)
        acc += as[row][k] * ws[k * HDIM + col];

    if (node < N_NODES) {
        h2[node * HDIM + col] = acc;
        float di = dinv[node];
        out[node * HDIM + col] = acc * di * di + b2[col];
    }
}

// ---------------- launch ----------------

extern "C" void kernel_launch(void* const* d_in, const int* in_sizes, int n_in,
                              void* d_out, int out_size, void* d_ws, size_t ws_size,
                              hipStream_t stream) {
    const float* x   = (const float*)d_in[0];
    const int*   ei  = (const int*)d_in[1];
    const float* W1  = (const float*)d_in[2];
    const float* b1  = (const float*)d_in[3];
    const float* W2  = (const float*)d_in[4];
    const float* b2  = (const float*)d_in[5];
    float* out = (float*)d_out;

    const int E = in_sizes[1] / 2;
    const int* src = ei;
    const int* dst = ei + E;

    // workspace layout (bytes)
    char* wsb = (char*)d_ws;
    float* dinv = (float*)(wsb);                         // 100k floats (deg then dinv, in place)
    float* h1   = (float*)(wsb + (1u << 20));            // 6.4 MB
    float* out1 = (float*)(wsb + (8u << 20));            // 6.4 MB
    float* h2   = (float*)(wsb + (16u << 20));           // 6.4 MB

    const int nodeBlocks = (N_NODES + 255) / 256;
    const int tileBlocks = (N_NODES + 15) / 16;
    const int edgeBlocks = (int)(((long long)E * HDIM + 255) / 256);
    const int cntBlocks  = (E + 255) / 256;

    k_fill1<<<nodeBlocks, 256, 0, stream>>>(dinv, N_NODES);
    k_count<<<cntBlocks, 256, 0, stream>>>(dst, dinv, E);
    k_rsqrt<<<nodeBlocks, 256, 0, stream>>>(dinv, N_NODES);

    k_h1<<<tileBlocks, 256, 0, stream>>>(x, W1, b1, dinv, h1, out1);
    k_edge<<<edgeBlocks, 256, 0, stream>>>(src, dst, dinv, h1, out1, E);

    k_h2<<<tileBlocks, 256, 0, stream>>>(out1, W2, b2, dinv, h2, out);
    k_edge<<<edgeBlocks, 256, 0, stream>>>(src, dst, dinv, h2, out, E);
}